// Round 4
// baseline (13802.844 us; speedup 1.0000x reference)
//
#include <hip/hip_runtime.h>

typedef unsigned short u16;
typedef unsigned int u32;
typedef unsigned long long u64;
typedef short short8 __attribute__((ext_vector_type(8)));   // 8 bf16 bit-patterns
typedef float f32x4 __attribute__((ext_vector_type(4)));

#define B_ 64
#define T_ 512
#define H_ 512
#define DIN_ 320
#define G4_ 2048
#define NTOK_ 50000
#define P_ 64        // participating scan blocks
#define LB_ 512      // launched blocks (2 per CU, 64 per XCD by capacity)

// ---- ws offsets (bytes) ----
#define OFF_CTRL  0         // u32[256]: [2..8] maxabs, scales @ word 16..21, claim @ 24..36
#define OFF_FLAG1 1024      // u64[64][8]
#define OFF_FLAG2 5120
#define OFF_FLAG3 9216
#define OFF_FLAG4 13312
#define OFF_PROBE 17408     // u64[64][8]
#define OFF_NLL   21504
#define OFF_BIAS  21760     // f32[2048]
#define OFF_HBUF  30720     // u16[64][512]
#define OFF_RESF  96256     // f32[64][512]
#define OFF_WI8   227328    // u16[2048][320]
#define OFF_WH8   1538048   // u16[2048][512]
#define OFF_INP   3635200   // u16[512][64][320]
#define OFF_LOG   24606720  // f32[64][50000]  (end ~35.7 MiB)

__device__ inline u16 f2b_exact(float f) { return (u16)(__float_as_uint(f) >> 16); }
__device__ inline float fqv(float x, float s) { return fminf(fmaxf(rintf(x / s), -128.f), 127.f) * s; }
__device__ inline float sigm(float x) { return 1.f / (1.f + expf(-x)); }
__device__ inline float wredmax(float v) {
#pragma unroll
  for (int d = 1; d < 64; d <<= 1) v = fmaxf(v, __shfl_xor(v, d, 64));
  return v;
}
__device__ inline f32x4 MFMA(short8 a, short8 b, f32x4 c) {
  return __builtin_amdgcn_mfma_f32_16x16x32_bf16(a, b, c, 0, 0, 0);
}
__device__ inline float bredmax(float v, float* red) {
  int tid = threadIdx.x;
  red[tid] = v; __syncthreads();
  for (int s = 128; s > 0; s >>= 1) { if (tid < s) red[tid] = fmaxf(red[tid], red[tid + s]); __syncthreads(); }
  float r = red[0]; __syncthreads();
  return r;
}

// ---- agent-scope (LLC) ops: R3-proven ----
__device__ inline void stF_ag(u64* p, u64 v) {
  __hip_atomic_store(p, v, __ATOMIC_RELAXED, __HIP_MEMORY_SCOPE_AGENT);
}
__device__ inline u64 ldF_ag(u64* p) {
  return __hip_atomic_load(p, __ATOMIC_RELAXED, __HIP_MEMORY_SCOPE_AGENT);
}
__device__ inline void st_h_ag(u16* p, u16 v) {
  __hip_atomic_store(p, v, __ATOMIC_RELAXED, __HIP_MEMORY_SCOPE_AGENT);
}
__device__ inline u64 ld_h64_ag(const u16* p) {
  return __hip_atomic_load((const u64*)p, __ATOMIC_RELAXED, __HIP_MEMORY_SCOPE_AGENT);
}

// ---- L2-scope (sc0: bypass L1, served by same-XCD L2) ops ----
__device__ inline u64 ldF_l2(const u64* p) {
  u64 v;
  asm volatile("global_load_dwordx2 %0, %1, off sc0\n\ts_waitcnt vmcnt(0)"
               : "=&v"(v) : "v"(p) : "memory");
  return v;
}
__device__ inline void stF_l2(u64* p, u64 v) {
  asm volatile("global_store_dwordx2 %0, %1, off sc0" :: "v"(p), "v"(v) : "memory");
}
__device__ inline void st_h_l2(u16* p, u32 v) {
  asm volatile("global_store_short %0, %1, off sc0" :: "v"(p), "v"(v) : "memory");
}

// poll all 64 h fragments (16 x 16B at stride 64B) in one asm, one waitcnt
#define LDH16_L2(HP)                                                       \
  asm volatile(                                                            \
    "global_load_dwordx4 %0, %16, off sc0\n\t"                             \
    "global_load_dwordx4 %1, %16, off offset:64 sc0\n\t"                   \
    "global_load_dwordx4 %2, %16, off offset:128 sc0\n\t"                  \
    "global_load_dwordx4 %3, %16, off offset:192 sc0\n\t"                  \
    "global_load_dwordx4 %4, %16, off offset:256 sc0\n\t"                  \
    "global_load_dwordx4 %5, %16, off offset:320 sc0\n\t"                  \
    "global_load_dwordx4 %6, %16, off offset:384 sc0\n\t"                  \
    "global_load_dwordx4 %7, %16, off offset:448 sc0\n\t"                  \
    "global_load_dwordx4 %8, %16, off offset:512 sc0\n\t"                  \
    "global_load_dwordx4 %9, %16, off offset:576 sc0\n\t"                  \
    "global_load_dwordx4 %10, %16, off offset:640 sc0\n\t"                 \
    "global_load_dwordx4 %11, %16, off offset:704 sc0\n\t"                 \
    "global_load_dwordx4 %12, %16, off offset:768 sc0\n\t"                 \
    "global_load_dwordx4 %13, %16, off offset:832 sc0\n\t"                 \
    "global_load_dwordx4 %14, %16, off offset:896 sc0\n\t"                 \
    "global_load_dwordx4 %15, %16, off offset:960 sc0\n\t"                 \
    "s_waitcnt vmcnt(0)"                                                   \
    : "=&v"(hh0), "=&v"(hh1), "=&v"(hh2), "=&v"(hh3),                      \
      "=&v"(hh4), "=&v"(hh5), "=&v"(hh6), "=&v"(hh7),                      \
      "=&v"(hh8), "=&v"(hh9), "=&v"(hh10), "=&v"(hh11),                    \
      "=&v"(hh12), "=&v"(hh13), "=&v"(hh14), "=&v"(hh15)                   \
    : "v"(HP) : "memory")

#define LDF6_L2(FB)                                                        \
  asm volatile(                                                            \
    "global_load_dwordx2 %0, %6, off sc0\n\t"                              \
    "global_load_dwordx2 %1, %6, off offset:8 sc0\n\t"                     \
    "global_load_dwordx2 %2, %6, off offset:16 sc0\n\t"                    \
    "global_load_dwordx2 %3, %6, off offset:24 sc0\n\t"                    \
    "global_load_dwordx2 %4, %6, off offset:32 sc0\n\t"                    \
    "global_load_dwordx2 %5, %6, off offset:40 sc0\n\t"                    \
    "s_waitcnt vmcnt(0)"                                                   \
    : "=&v"(a0), "=&v"(a1), "=&v"(a2), "=&v"(a3), "=&v"(a4), "=&v"(a5)     \
    : "v"(FB) : "memory")

// ---------- zero ctrl+flags+probe and hBuf ----------
__global__ void kInit(u32* w32, u32* hbuf32) {
  int i = blockIdx.x * blockDim.x + threadIdx.x, st = gridDim.x * blockDim.x;
  for (int j = i; j < 5376; j += st) w32[j] = 0u;          // 21504 B
  for (int j = i; j < B_ * H_ / 2; j += st) hbuf32[j] = 0u;
}

// ---------- maxabs over f32 tensor ----------
__global__ void kMaxAbs(const float* p, int n4, u32* slot) {
  __shared__ float red[256];
  int i0 = blockIdx.x * blockDim.x + threadIdx.x, st = gridDim.x * blockDim.x;
  float m = 0.f;
  const float4* p4 = (const float4*)p;
  for (int i = i0; i < n4; i += st) {
    float4 v = p4[i];
    m = fmaxf(fmaxf(m, fmaxf(fabsf(v.x), fabsf(v.y))), fmaxf(fabsf(v.z), fabsf(v.w)));
  }
  m = bredmax(m, red);
  if (threadIdx.x == 0) atomicMax(slot, __float_as_uint(m));
}

// ---------- maxabs over gathered embedding rows ----------
__global__ void kGatherMax(const int* x, const int* y, const float* emb_tok, const float* emb_lab, u32* ctrl) {
  __shared__ float red[256];
  int tid = threadIdx.x;
  float mt = 0.f, ml = 0.f;
  for (int p = blockIdx.x; p < B_ * T_; p += gridDim.x)
    mt = fmaxf(mt, fabsf(emb_tok[(size_t)x[p] * 256 + tid]));
  for (int p = blockIdx.x; p < B_; p += gridDim.x)
    if (tid < 64) ml = fmaxf(ml, fabsf(emb_lab[y[p] * 64 + tid]));
  float m = bredmax(mt, red);
  if (tid == 0) atomicMax(&ctrl[7], __float_as_uint(m));
  m = bredmax(ml, red);
  if (tid == 0) atomicMax(&ctrl[8], __float_as_uint(m));
}

// ---------- per-tensor scales ----------
__global__ void kScalars(u32* ctrl) {
  float* s = (float*)(ctrl + 16);
  float mt = __uint_as_float(ctrl[2]), ml = __uint_as_float(ctrl[3]);
  float mwi = __uint_as_float(ctrl[4]), mwh = __uint_as_float(ctrl[5]), mwd = __uint_as_float(ctrl[6]);
  float mtg = __uint_as_float(ctrl[7]), mlg = __uint_as_float(ctrl[8]);
  float s_tok = fmaxf(mt, 1e-8f) / 127.f, s_lab = fmaxf(ml, 1e-8f) / 127.f;
  s[0] = s_tok; s[1] = s_lab;
  s[2] = fmaxf(mwi, 1e-8f) / 127.f;
  s[3] = fmaxf(mwh, 1e-8f) / 127.f;
  s[4] = fmaxf(mwd, 1e-8f) / 127.f;
  float qt = fminf(rintf(mtg / s_tok), 127.f) * s_tok;
  float ql = fminf(rintf(mlg / s_lab), 127.f) * s_lab;
  s[5] = fmaxf(fmaxf(qt, ql), 1e-8f) / 127.f;
}

// ---------- double-quantized input -> int-valued bf16, layout [t][b][d] ----------
__global__ void kBuildInp(const int* x, const int* y, const float* emb_tok, const float* emb_lab,
                          const u32* ctrl, u16* inp) {
  const float* s = (const float*)(ctrl + 16);
  float s_tok = s[0], s_lab = s[1], s_inp = s[5];
  int p = blockIdx.x, b = p >> 9, t = p & 511, d = threadIdx.x;
  float v, s1;
  if (d < 256) { v = emb_tok[(size_t)x[p] * 256 + d]; s1 = s_tok; }
  else         { v = emb_lab[y[b] * 64 + (d - 256)];  s1 = s_lab; }
  float q1 = fminf(fmaxf(rintf(v / s1), -128.f), 127.f) * s1;
  float k2 = fminf(fmaxf(rintf(q1 / s_inp), -128.f), 127.f);
  inp[((size_t)t * B_ + b) * DIN_ + d] = f2b_exact(k2);
}

// ---------- quantize Wi/Wh; build bias ----------
__global__ void kQuantW(const float* Wi, const float* Wh, const float* bi, const float* bh,
                        const u32* ctrl, u16* wi8, u16* wh8, float* biasF) {
  const float* s = (const float*)(ctrl + 16);
  float sWi = s[2], sWh = s[3];
  const int NA = G4_ * DIN_, NB = G4_ * H_;
  int i0 = blockIdx.x * blockDim.x + threadIdx.x, st = gridDim.x * blockDim.x;
  for (int i = i0; i < NA + NB + G4_; i += st) {
    if (i < NA) {
      wi8[i] = f2b_exact(fminf(fmaxf(rintf(Wi[i] / sWi), -128.f), 127.f));
    } else if (i < NA + NB) {
      int j = i - NA;
      wh8[j] = f2b_exact(fminf(fmaxf(rintf(Wh[j] / sWh), -128.f), 127.f));
    } else {
      int r = i - NA - NB;
      biasF[r] = bi[r] + bh[r];
    }
  }
}

// ---------- the scan t-loop, flavored by L2M (1 = same-XCD sc0 ops, 0 = agent/LLC) ----------
template <int L2M>
__device__ void scanBody(const u16* inp8, u64* flag1, u64* flag2, u64* flag3, u64* flag4,
                         u16* hBuf, float* resF,
                         const u16* ldsWi, const u16* ldsWh,
                         float (*actT)[66], const float* biasT, float (*sRed)[8],
                         int blk, float sA, float sWh) {
  const int tid = threadIdx.x, lane = tid & 63, wid = tid >> 6;
  const int quad = lane >> 4, l15 = lane & 15;
  const int hb = blk * 8;
  const int m0 = wid * 16;
  const int jj0 = tid & 7, b0 = tid >> 3;
  const int jj1 = (tid + 256) & 7, b1 = (tid + 256) >> 3;
  float cReg[2] = {0.f, 0.f};
  float hFirst[2] = {0.f, 0.f};
  float s_h_prev = 1.0f;

  // input-contribution accumulators for t=0
  f32x4 nA0 = {0.f, 0.f, 0.f, 0.f}, nA1 = {0.f, 0.f, 0.f, 0.f};
  {
    const u16* ip = inp8 + ((size_t)(m0 + l15)) * DIN_ + quad * 8;
#pragma unroll
    for (int ks = 0; ks < 10; ++ks) {
      short8 a = *(const short8*)(ip + ks * 32);
      nA0 = MFMA(a, *(const short8*)&ldsWi[(ks * 64 + lane) * 8], nA0);
      nA1 = MFMA(a, *(const short8*)&ldsWi[((10 + ks) * 64 + lane) * 8], nA1);
    }
  }

  for (int t = 0; t < T_; ++t) {
    const u32 sq = (u32)(t * 4);
    f32x4 aA0 = nA0, aA1 = nA1;

    // ===== wait for h publish of t-1 =====
    if (t > 0) {
      u64* f4 = flag4 + lane * 8;
      for (;;) {
        u64 v = L2M ? ldF_l2(f4) : ldF_ag(f4);
        if ((u32)(v >> 32) == sq) break;
        __builtin_amdgcn_s_sleep(L2M ? 1 : 4);
      }
      __builtin_amdgcn_sched_barrier(0);
    }

    // ===== stage 1: recurrent GEMM =====
    f32x4 aB0 = {0.f,0.f,0.f,0.f}, aB1 = {0.f,0.f,0.f,0.f};
    const u16* hp = hBuf + (size_t)(m0 + l15) * H_ + quad * 8;
    if constexpr (L2M) {
      short8 hh0, hh1, hh2, hh3, hh4, hh5, hh6, hh7;
      short8 hh8, hh9, hh10, hh11, hh12, hh13, hh14, hh15;
      LDH16_L2(hp);
#define MMK(K, HK)                                                         \
      aB0 = MFMA(HK, *(const short8*)&ldsWh[((K) * 64 + lane) * 8], aB0);  \
      aB1 = MFMA(HK, *(const short8*)&ldsWh[(((K) + 16) * 64 + lane) * 8], aB1);
      MMK(0, hh0)  MMK(1, hh1)  MMK(2, hh2)  MMK(3, hh3)
      MMK(4, hh4)  MMK(5, hh5)  MMK(6, hh6)  MMK(7, hh7)
      MMK(8, hh8)  MMK(9, hh9)  MMK(10, hh10) MMK(11, hh11)
      MMK(12, hh12) MMK(13, hh13) MMK(14, hh14) MMK(15, hh15)
#undef MMK
    } else {
#pragma unroll
      for (int ks = 0; ks < 16; ++ks) {
        u64 w0 = ld_h64_ag(hp + ks * 32);
        u64 w1 = ld_h64_ag(hp + ks * 32 + 4);
        short8 a;
        ((u64*)&a)[0] = w0;
        ((u64*)&a)[1] = w1;
        aB0 = MFMA(a, *(const short8*)&ldsWh[(ks * 64 + lane) * 8], aB0);
        aB1 = MFMA(a, *(const short8*)&ldsWh[((16 + ks) * 64 + lane) * 8], aB1);
      }
    }
    const float sB_ = s_h_prev * sWh;
    float vabs = 0.f, v0mx = -3e38f, v1mx = -3e38f, v1mn = 3e38f;
#pragma unroll
    for (int reg = 0; reg < 4; ++reg) {
      int m = m0 + quad * 4 + reg;
      float p0 = biasT[l15] + sA * aA0[reg] + sB_ * aB0[reg];        // gates i|f
      float p1 = biasT[16 + l15] + sA * aA1[reg] + sB_ * aB1[reg];   // gates g|o
      actT[l15][m] = p0; actT[16 + l15][m] = p1;
      vabs = fmaxf(vabs, fmaxf(fabsf(p0), fabsf(p1)));
      v0mx = fmaxf(v0mx, p0);
      v1mx = fmaxf(v1mx, p1);
      v1mn = fminf(v1mn, p1);
    }
    bool lo = (l15 < 8);
    float q[6];
    q[0] = vabs;
    q[1] = lo ? v0mx : -3e38f;
    q[2] = lo ? -3e38f : v0mx;
    q[3] = lo ? -3e38f : v1mx;
    q[4] = lo ? v1mx : -3e38f;
    q[5] = lo ? -v1mn : -3e38f;
#pragma unroll
    for (int d = 1; d < 64; d <<= 1) {
#pragma unroll
      for (int k = 0; k < 6; ++k) q[k] = fmaxf(q[k], __shfl_xor(q[k], d, 64));
    }
    if (lane == 0) {
#pragma unroll
      for (int k = 0; k < 6; ++k) sRed[wid][k] = q[k];
    }
    __syncthreads();
    if (tid < 6) {
      float m = fmaxf(fmaxf(sRed[0][tid], sRed[1][tid]), fmaxf(sRed[2][tid], sRed[3][tid]));
      u64 pv = (((u64)(sq + 1)) << 32) | (u64)__float_as_uint(m);
      if (L2M) stF_l2(flag1 + blk * 8 + tid, pv); else stF_ag(flag1 + blk * 8 + tid, pv);
    }
    // poll flag1: lane l watches block l
    u64 a0, a1, a2, a3, a4, a5;
    {
      u64* fb = flag1 + lane * 8;
      const u32 e = sq + 1;
      for (;;) {
        if constexpr (L2M) {
          LDF6_L2(fb);
        } else {
          a0 = ldF_ag(fb + 0); a1 = ldF_ag(fb + 1); a2 = ldF_ag(fb + 2);
          a3 = ldF_ag(fb + 3); a4 = ldF_ag(fb + 4); a5 = ldF_ag(fb + 5);
        }
        if ((u32)(a0 >> 32) == e && (u32)(a1 >> 32) == e && (u32)(a2 >> 32) == e &&
            (u32)(a3 >> 32) == e && (u32)(a4 >> 32) == e && (u32)(a5 >> 32) == e) break;
        __builtin_amdgcn_s_sleep(L2M ? 1 : 4);
      }
    }
    float g0 = __uint_as_float((u32)a0), g1 = __uint_as_float((u32)a1),
          g2 = __uint_as_float((u32)a2), g3 = __uint_as_float((u32)a3),
          g4 = __uint_as_float((u32)a4), g5 = __uint_as_float((u32)a5);
#pragma unroll
    for (int d = 1; d < 64; d <<= 1) {
      g0 = fmaxf(g0, __shfl_xor(g0, d, 64));
      g1 = fmaxf(g1, __shfl_xor(g1, d, 64));
      g2 = fmaxf(g2, __shfl_xor(g2, d, 64));
      g3 = fmaxf(g3, __shfl_xor(g3, d, 64));
      g4 = fmaxf(g4, __shfl_xor(g4, d, 64));
      g5 = fmaxf(g5, __shfl_xor(g5, d, 64));
    }
    const float s_g = fmaxf(g0, 1e-8f) / 127.f;
    const float mi = g1, mf = g2, mo = g3, mg = g4, mgn = -g5;
    const float s_i = fmaxf(sigm(fqv(mi, s_g)), 1e-8f) / 255.f;
    const float s_f = fmaxf(sigm(fqv(mf, s_g)), 1e-8f) / 255.f;
    const float s_o = fmaxf(sigm(fqv(mo, s_g)), 1e-8f) / 255.f;
    const float ga = fmaxf(fabsf(fqv(mg, s_g)), fabsf(fqv(mgn, s_g)));
    const float s_gt = fmaxf(tanhf(ga), 1e-8f) / 127.f;

    // ===== stage 2: activations + cell update =====
    float oqv[2];
    {
      float vi = sigm(fqv(actT[jj0][b0], s_g));
      float vf = sigm(fqv(actT[8 + jj0][b0], s_g));
      float vg = tanhf(fqv(actT[16 + jj0][b0], s_g));
      float vo = sigm(fqv(actT[24 + jj0][b0], s_g));
      float iq = fminf(fmaxf(rintf(vi / s_i), 0.f), 255.f) * s_i;
      float fq = fminf(fmaxf(rintf(vf / s_f), 0.f), 255.f) * s_f;
      float gq = fminf(fmaxf(rintf(vg / s_gt), -128.f), 127.f) * s_gt;
      oqv[0] = fminf(fmaxf(rintf(vo / s_o), 0.f), 255.f) * s_o;
      cReg[0] = fq * cReg[0] + iq * gq;
      vi = sigm(fqv(actT[jj1][b1], s_g));
      vf = sigm(fqv(actT[8 + jj1][b1], s_g));
      vg = tanhf(fqv(actT[16 + jj1][b1], s_g));
      vo = sigm(fqv(actT[24 + jj1][b1], s_g));
      iq = fminf(fmaxf(rintf(vi / s_i), 0.f), 255.f) * s_i;
      fq = fminf(fmaxf(rintf(vf / s_f), 0.f), 255.f) * s_f;
      gq = fminf(fmaxf(rintf(vg / s_gt), -128.f), 127.f) * s_gt;
      oqv[1] = fminf(fmaxf(rintf(vo / s_o), 0.f), 255.f) * s_o;
      cReg[1] = fq * cReg[1] + iq * gq;
    }
    float lm = wredmax(fmaxf(fabsf(cReg[0]), fabsf(cReg[1])));
    if (lane == 0) sRed[wid][0] = lm;
    __syncthreads();
    if (tid == 0) {
      float m = fmaxf(fmaxf(sRed[0][0], sRed[1][0]), fmaxf(sRed[2][0], sRed[3][0]));
      u64 pv = (((u64)(sq + 2)) << 32) | (u64)__float_as_uint(m);
      if (L2M) stF_l2(flag2 + blk * 8, pv); else stF_ag(flag2 + blk * 8, pv);
    }
    float maxc;
    {
      u64* f2 = flag2 + lane * 8;
      u64 v;
      for (;;) {
        v = L2M ? ldF_l2(f2) : ldF_ag(f2);
        if ((u32)(v >> 32) == sq + 2) break;
        __builtin_amdgcn_s_sleep(L2M ? 1 : 4);
      }
      maxc = __uint_as_float((u32)v);
    }
#pragma unroll
    for (int d = 1; d < 64; d <<= 1) maxc = fmaxf(maxc, __shfl_xor(maxc, d, 64));
    const float s_t = fmaxf(tanhf(maxc), 1e-8f) / 127.f;

    // ===== stage 3: hp = oq * fq(tanh c) =====
    float hpv[2];
    hpv[0] = oqv[0] * fqv(tanhf(cReg[0]), s_t);
    hpv[1] = oqv[1] * fqv(tanhf(cReg[1]), s_t);
    lm = wredmax(fmaxf(fabsf(hpv[0]), fabsf(hpv[1])));
    if (lane == 0) sRed[wid][0] = lm;
    __syncthreads();
    if (tid == 0) {
      float m = fmaxf(fmaxf(sRed[0][0], sRed[1][0]), fmaxf(sRed[2][0], sRed[3][0]));
      u64 pv = (((u64)(sq + 3)) << 32) | (u64)__float_as_uint(m);
      if (L2M) stF_l2(flag3 + blk * 8, pv); else stF_ag(flag3 + blk * 8, pv);
    }
    float maxhp;
    {
      u64* f3 = flag3 + lane * 8;
      u64 v;
      for (;;) {
        v = L2M ? ldF_l2(f3) : ldF_ag(f3);
        if ((u32)(v >> 32) == sq + 3) break;
        __builtin_amdgcn_s_sleep(L2M ? 1 : 4);
      }
      maxhp = __uint_as_float((u32)v);
    }
#pragma unroll
    for (int d = 1; d < 64; d <<= 1) maxhp = fmaxf(maxhp, __shfl_xor(maxhp, d, 64));
    const float s_h = fmaxf(maxhp, 1e-8f) / 127.f;

    // ===== stage 4: h = fq(hp); publish =====
    {
      float hi = fminf(fmaxf(rintf(hpv[0] / s_h), -128.f), 127.f);
      if (L2M) st_h_l2(hBuf + b0 * H_ + hb + jj0, (u32)f2b_exact(hi));
      else     st_h_ag(hBuf + b0 * H_ + hb + jj0, f2b_exact(hi));
      float hv = hi * s_h;
      if (t == 0) hFirst[0] = hv;
      if (t == T_ - 1) resF[b0 * H_ + hb + jj0] = 0.5f * (hFirst[0] + hv);
      hi = fminf(fmaxf(rintf(hpv[1] / s_h), -128.f), 127.f);
      if (L2M) st_h_l2(hBuf + b1 * H_ + hb + jj1, (u32)f2b_exact(hi));
      else     st_h_ag(hBuf + b1 * H_ + hb + jj1, f2b_exact(hi));
      hv = hi * s_h;
      if (t == 0) hFirst[1] = hv;
      if (t == T_ - 1) resF[b1 * H_ + hb + jj1] = 0.5f * (hFirst[1] + hv);
    }
    s_h_prev = s_h;
    if (t < T_ - 1) {
      if (L2M) asm volatile("s_waitcnt vmcnt(0)" ::: "memory");  // drain asm h-stores
      __syncthreads();
      if (tid == 0) {
        u64 pv = (((u64)(sq + 4)) << 32) | 1u;
        if (L2M) stF_l2(flag4 + blk * 8, pv); else stF_ag(flag4 + blk * 8, pv);
      }
      // input-contribution GEMM for t+1 (hidden under the publish wait)
      nA0 = (f32x4){0.f, 0.f, 0.f, 0.f};
      nA1 = (f32x4){0.f, 0.f, 0.f, 0.f};
      const u16* ip = inp8 + ((size_t)(t + 1) * B_ + m0 + l15) * DIN_ + quad * 8;
#pragma unroll
      for (int ks = 0; ks < 10; ++ks) {
        short8 a = *(const short8*)(ip + ks * 32);
        nA0 = MFMA(a, *(const short8*)&ldsWi[(ks * 64 + lane) * 8], nA0);
        nA1 = MFMA(a, *(const short8*)&ldsWi[((10 + ks) * 64 + lane) * 8], nA1);
      }
    }
  }
}

// ---------- persistent MFMA scan with XCD-local fast path ----------
__global__ __launch_bounds__(256, 2) void kScan(
    const u16* inp8, const u16* wi8, const u16* wh8, const float* biasF,
    u32* ctrl, u64* flag1, u64* flag2, u64* flag3, u64* flag4, u64* probeF,
    u16* hBuf, float* resF) {
  __shared__ u16 ldsWi[20 * 64 * 8];
  __shared__ u16 ldsWh[32 * 64 * 8];
  __shared__ float actT[32][66];
  __shared__ float biasT[32];
  __shared__ float sRed[4][8];
  __shared__ int sInfo[2];

  const int tid = threadIdx.x;

  // ---- claim: rank within my XCD; leader picks an XCD with >=64 blocks ----
  if (tid == 0) {
    u32 xcc;
    asm volatile("s_getreg_b32 %0, hwreg(HW_REG_XCC_ID)" : "=s"(xcc));
    xcc &= 7u;
    u32 rank = __hip_atomic_fetch_add(&ctrl[24 + xcc], 1u, __ATOMIC_RELAXED, __HIP_MEMORY_SCOPE_AGENT);
    __hip_atomic_fetch_add(&ctrl[36], 1u, __ATOMIC_RELEASE, __HIP_MEMORY_SCOPE_AGENT);
    if (blockIdx.x == 0) {
      while (__hip_atomic_load(&ctrl[36], __ATOMIC_ACQUIRE, __HIP_MEMORY_SCOPE_AGENT) < (u32)LB_)
        __builtin_amdgcn_s_sleep(8);
      u32 pick = 0;
      for (u32 x2 = 0; x2 < 8; ++x2) {
        u32 c = __hip_atomic_load(&ctrl[24 + x2], __ATOMIC_RELAXED, __HIP_MEMORY_SCOPE_AGENT);
        if (c >= (u32)P_) { pick = x2 + 1u; break; }
      }
      __hip_atomic_store(&ctrl[33], pick, __ATOMIC_RELAXED, __HIP_MEMORY_SCOPE_AGENT);
    }
    u32 pick;
    for (;;) {
      pick = __hip_atomic_load(&ctrl[33], __ATOMIC_RELAXED, __HIP_MEMORY_SCOPE_AGENT);
      if (pick) break;
      __builtin_amdgcn_s_sleep(8);
    }
    sInfo[0] = (pick != 0 && xcc == pick - 1u && rank < (u32)P_) ? (int)rank : -1;
  }
  __syncthreads();
  const int cand = sInfo[0];

  // ---- probe: verify sc0 store->cross-CU-load visibility, incl. warm-line epoch 2 ----
  if (cand >= 0) {
    const int lane = tid & 63, wid = tid >> 6;
    if (tid == 0) stF_l2(probeF + cand * 8, (1ULL << 48) | 1ULL);
    u64 t0 = __builtin_amdgcn_s_memrealtime();
    int mine = 0;
    for (;;) {
      u64 v = ldF_l2(probeF + lane * 8);
      if ((v >> 48) >= 1ULL) { mine = 1; break; }
      if (__builtin_amdgcn_s_memrealtime() - t0 > 300000ULL) break;  // ~3 ms @100MHz
      __builtin_amdgcn_s_sleep(8);
    }
    if (tid == 0 && mine) stF_l2(probeF + cand * 8, (2ULL << 48) | 1ULL);  // warm-line epoch
    int mine2 = 0;
    if (mine) {
      t0 = __builtin_amdgcn_s_memrealtime();
      for (;;) {
        u64 v = ldF_l2(probeF + lane * 8);
        if ((v >> 48) >= 2ULL) { mine2 = 1; break; }
        if (__builtin_amdgcn_s_memrealtime() - t0 > 300000ULL) break;
        __builtin_amdgcn_s_sleep(8);
      }
    }
    int aw = __all(mine & mine2);
    if (lane == 0) sRed[wid][0] = (float)aw;
    __syncthreads();
    if (tid == 0) {
      int ok = (sRed[0][0] != 0.f) && (sRed[1][0] != 0.f) && (sRed[2][0] != 0.f) && (sRed[3][0] != 0.f);
      if (!ok) __hip_atomic_fetch_or(&ctrl[34], 1u, __ATOMIC_RELAXED, __HIP_MEMORY_SCOPE_AGENT);
      __hip_atomic_fetch_add(&ctrl[35], 1u, __ATOMIC_RELEASE, __HIP_MEMORY_SCOPE_AGENT);
    }
    __syncthreads();
  }

  // ---- everyone: wait for the vote, decide flavor + participation ----
  if (tid == 0) {
    while (__hip_atomic_load(&ctrl[35], __ATOMIC_ACQUIRE, __HIP_MEMORY_SCOPE_AGENT) < (u32)P_)
      __builtin_amdgcn_s_sleep(8);
    u32 fv = __hip_atomic_load(&ctrl[34], __ATOMIC_RELAXED, __HIP_MEMORY_SCOPE_AGENT);
    sInfo[1] = (fv == 0u) ? 1 : 0;
  }
  __syncthreads();
  const int l2mode = sInfo[1];
  const int blk = l2mode ? cand : ((int)blockIdx.x < P_ ? (int)blockIdx.x : -1);
  if (blk < 0) return;

  // ---- stage weights into LDS ----
  const int lane = tid & 63, wid = tid >> 6;
  const int quad = lane >> 4, l15 = lane & 15;
  const int hb = blk * 8;
  const float* scal = (const float*)(ctrl + 16);
  const float sWi = scal[2], sWh = scal[3], s_inp = scal[5];
  const float sA = s_inp * sWi;

  for (int fid = wid; fid < 20; fid += 4) {
    int nt = fid / 10, ks = fid - nt * 10;
    int n = nt * 16 + l15, r = (n >> 3) * 512 + hb + (n & 7);
    *(uint4*)&ldsWi[(fid * 64 + lane) * 8] = *(const uint4*)(wi8 + (size_t)r * DIN_ + ks * 32 + quad * 8);
  }
  for (int fid = wid; fid < 32; fid += 4) {
    int nt = fid >> 4, ks = fid & 15;
    int n = nt * 16 + l15, r = (n >> 3) * 512 + hb + (n & 7);
    *(uint4*)&ldsWh[(fid * 64 + lane) * 8] = *(const uint4*)(wh8 + (size_t)r * H_ + ks * 32 + quad * 8);
  }
  if (tid < 32) { int r = (tid >> 3) * 512 + hb + (tid & 7); biasT[tid] = biasF[r]; }
  __syncthreads();

  if (l2mode)
    scanBody<1>(inp8, flag1, flag2, flag3, flag4, hBuf, resF, ldsWi, ldsWh, actT, biasT, sRed, blk, sA, sWh);
  else
    scanBody<0>(inp8, flag1, flag2, flag3, flag4, hBuf, resF, ldsWi, ldsWh, actT, biasT, sRed, blk, sA, sWh);
}

// ---------- decode GEMM ----------
__global__ __launch_bounds__(256) void kDecode(const float* resF, const float* Wdec,
                                               const u32* ctrl, float* logits) {
  const float sWd = ((const float*)(ctrl + 16))[4];
  int c = blockIdx.x * 256 + threadIdx.x;
  if (c >= NTOK_) return;
  const float4* wrow = (const float4*)(Wdec + (size_t)c * H_);
  float acc[64];
#pragma unroll
  for (int rr = 0; rr < 64; rr++) acc[rr] = 0.f;
  for (int k4 = 0; k4 < H_ / 4; k4++) {
    float4 w = wrow[k4];
    float w0 = fminf(fmaxf(rintf(w.x / sWd), -128.f), 127.f) * sWd;
    float w1 = fminf(fmaxf(rintf(w.y / sWd), -128.f), 127.f) * sWd;
    float w2 = fminf(fmaxf(rintf(w.z / sWd), -128.f), 127.f) * sWd;
    float w3 = fminf(fmaxf(rintf(w.w / sWd), -128.f), 127.f) * sWd;
    const float* rp = resF + k4 * 4;
#pragma unroll
    for (int rr = 0; rr < 64; rr++) {
      acc[rr] += rp[rr * H_ + 0] * w0 + rp[rr * H_ + 1] * w1 +
                 rp[rr * H_ + 2] * w2 + rp[rr * H_ + 3] * w3;
    }
  }
#pragma unroll
  for (int rr = 0; rr < 64; rr++) logits[(size_t)rr * NTOK_ + c] = acc[rr];
}

// ---------- per-row log-softmax NLL ----------
__global__ void kLoss(const float* logits, const int* x_pred, float* nll) {
  __shared__ float red[256];
  int b = blockIdx.x, tid = threadIdx.x;
  const float* row = logits + (size_t)b * NTOK_;
  float m = -3e38f;
  for (int i = tid; i < NTOK_; i += 256) m = fmaxf(m, row[i]);
  m = bredmax(m, red);
  float s = 0.f;
  for (int i = tid; i < NTOK_; i += 256) s += expf(row[i] - m);
  red[tid] = s; __syncthreads();
  for (int st = 128; st > 0; st >>= 1) { if (tid < st) red[tid] += red[tid + st]; __syncthreads(); }
  if (tid == 0) nll[b] = m + logf(red[0]) - row[x_pred[b]];
}

__global__ void kFinal(const float* nll, float* out) {
  float s = 0.f;
  for (int i = 0; i < B_; i++) s += nll[i];
  out[0] = s / 64.f;
}

extern "C" void kernel_launch(void* const* d_in, const int* in_sizes, int n_in,
                              void* d_out, int out_size, void* d_ws, size_t ws_size,
                              hipStream_t stream) {
  const int* x      = (const int*)d_in[0];
  const int* x_pred = (const int*)d_in[1];
  const int* y_ext  = (const int*)d_in[2];
  const float* emb_tok = (const float*)d_in[3];
  const float* emb_lab = (const float*)d_in[4];
  const float* Wi   = (const float*)d_in[5];
  const float* Wh   = (const float*)d_in[6];
  const float* bi   = (const float*)d_in[7];
  const float* bh   = (const float*)d_in[8];
  const float* Wdec = (const float*)d_in[9];

  char* W = (char*)d_ws;
  u32* ctrl    = (u32*)(W + OFF_CTRL);
  u64* flag1   = (u64*)(W + OFF_FLAG1);
  u64* flag2   = (u64*)(W + OFF_FLAG2);
  u64* flag3   = (u64*)(W + OFF_FLAG3);
  u64* flag4   = (u64*)(W + OFF_FLAG4);
  u64* probeF  = (u64*)(W + OFF_PROBE);
  float* nll   = (float*)(W + OFF_NLL);
  float* biasF = (float*)(W + OFF_BIAS);
  u16* hBuf    = (u16*)(W + OFF_HBUF);
  float* resF  = (float*)(W + OFF_RESF);
  u16* wi8     = (u16*)(W + OFF_WI8);
  u16* wh8     = (u16*)(W + OFF_WH8);
  u16* inp     = (u16*)(W + OFF_INP);
  float* logits = (float*)(W + OFF_LOG);

  kInit<<<128, 256, 0, stream>>>(ctrl, (u32*)hBuf);
  kMaxAbs<<<1024, 256, 0, stream>>>(emb_tok, NTOK_ * 256 / 4, ctrl + 2);
  kMaxAbs<<<1, 256, 0, stream>>>(emb_lab, 10 * 64 / 4, ctrl + 3);
  kMaxAbs<<<320, 256, 0, stream>>>(Wi, G4_ * DIN_ / 4, ctrl + 4);
  kMaxAbs<<<512, 256, 0, stream>>>(Wh, G4_ * H_ / 4, ctrl + 5);
  kMaxAbs<<<1024, 256, 0, stream>>>(Wdec, NTOK_ * H_ / 4, ctrl + 6);
  kGatherMax<<<256, 256, 0, stream>>>(x, y_ext, emb_tok, emb_lab, ctrl);
  kScalars<<<1, 1, 0, stream>>>(ctrl);
  kBuildInp<<<B_ * T_, DIN_, 0, stream>>>(x, y_ext, emb_tok, emb_lab, ctrl, inp);
  kQuantW<<<4096, 256, 0, stream>>>(Wi, Wh, bi, bh, ctrl, wi8, wh8, biasF);

  kScan<<<LB_, 256, 0, stream>>>(inp, wi8, wh8, biasF, ctrl,
                                 flag1, flag2, flag3, flag4, probeF, hBuf, resF);

  kDecode<<<(NTOK_ + 255) / 256, 256, 0, stream>>>(resF, Wdec, ctrl, logits);
  kLoss<<<B_, 256, 0, stream>>>(logits, x_pred, nll);
  kFinal<<<1, 1, 0, stream>>>(nll, (float*)d_out);
}

// Round 5
// 7543.517 us; speedup vs baseline: 1.8298x; 1.8298x over previous
//
#include <hip/hip_runtime.h>

typedef unsigned short u16;
typedef unsigned int u32;
typedef unsigned long long u64;
typedef short short8 __attribute__((ext_vector_type(8)));   // 8 bf16 bit-patterns
typedef float f32x4 __attribute__((ext_vector_type(4)));

#define B_ 64
#define T_ 512
#define H_ 512
#define DIN_ 320
#define G4_ 2048
#define NTOK_ 50000
#define P_ 64   // persistent scan blocks (<=256 CUs -> co-resident)

// ---- ws offsets (bytes) ----
#define OFF_CTRL  0         // u32[64]: [2..8] maxabs slots, f32 scales @ word 16..21
#define OFF_FLAG1 1024      // u64[64][8]: per-block stage-1 flags (6 payload u64 + pad to 64B)
#define OFF_FLAG2 5120      // u64[64][8]: stage-2 (cmax)
#define OFF_FLAG3 9216      // u64[64][8]: stage-3 (hpmax)
#define OFF_FLAG4 13312     // u64[64][8]: stage-4 (publish)
#define OFF_NLL   17408     // f32[64]
#define OFF_BIAS  17664     // f32[2048]
#define OFF_HBUF  26624     // u16[64][512] int-valued bf16 h
#define OFF_RESF  92160     // f32[64][512]
#define OFF_WI8   223232    // u16[2048][320] int-valued bf16
#define OFF_WH8   1533952   // u16[2048][512]
#define OFF_INP   3631104   // u16[512][64][320]
#define OFF_LOG   24602624  // f32[64][50000]

__device__ inline u16 f2b_exact(float f) { return (u16)(__float_as_uint(f) >> 16); }
__device__ inline float fqv(float x, float s) { return fminf(fmaxf(rintf(x / s), -128.f), 127.f) * s; }
__device__ inline float sigm(float x) { return 1.f / (1.f + expf(-x)); }
__device__ inline float wredmax(float v) {
#pragma unroll
  for (int d = 1; d < 64; d <<= 1) v = fmaxf(v, __shfl_xor(v, d, 64));
  return v;
}
__device__ inline f32x4 MFMA(short8 a, short8 b, f32x4 c) {
  return __builtin_amdgcn_mfma_f32_16x16x32_bf16(a, b, c, 0, 0, 0);
}
__device__ inline float bredmax(float v, float* red) {
  int tid = threadIdx.x;
  red[tid] = v; __syncthreads();
  for (int s = 128; s > 0; s >>= 1) { if (tid < s) red[tid] = fmaxf(red[tid], red[tid + s]); __syncthreads(); }
  float r = red[0]; __syncthreads();
  return r;
}

// self-validating flag ops: u64 = (epoch << 32) | payload_bits, relaxed agent scope
__device__ inline void st_flag(u64* p, u64 v) {
  __hip_atomic_store(p, v, __ATOMIC_RELAXED, __HIP_MEMORY_SCOPE_AGENT);
}
__device__ inline u64 ld_flag(u64* p) {
  return __hip_atomic_load(p, __ATOMIC_RELAXED, __HIP_MEMORY_SCOPE_AGENT);
}
// agent-scope (LLC-direct) data access for hBuf: no cache maintenance needed
__device__ inline void st_h(u16* p, u16 v) {
  __hip_atomic_store(p, v, __ATOMIC_RELAXED, __HIP_MEMORY_SCOPE_AGENT);
}
__device__ inline u64 ld_h64(const u16* p) {
  return __hip_atomic_load((const u64*)p, __ATOMIC_RELAXED, __HIP_MEMORY_SCOPE_AGENT);
}

// ---------- zero ctrl+flags and hBuf ----------
__global__ void kInit(u32* w32, u32* hbuf32) {
  int i = blockIdx.x * blockDim.x + threadIdx.x, st = gridDim.x * blockDim.x;
  for (int j = i; j < 4352; j += st) w32[j] = 0u;          // 17408 B: ctrl + 4 flag arrays
  for (int j = i; j < B_ * H_ / 2; j += st) hbuf32[j] = 0u;
}

// ---------- maxabs over f32 tensor (n4 float4 chunks) ----------
__global__ void kMaxAbs(const float* p, int n4, u32* slot) {
  __shared__ float red[256];
  int i0 = blockIdx.x * blockDim.x + threadIdx.x, st = gridDim.x * blockDim.x;
  float m = 0.f;
  const float4* p4 = (const float4*)p;
  for (int i = i0; i < n4; i += st) {
    float4 v = p4[i];
    m = fmaxf(fmaxf(m, fmaxf(fabsf(v.x), fabsf(v.y))), fmaxf(fabsf(v.z), fabsf(v.w)));
  }
  m = bredmax(m, red);
  if (threadIdx.x == 0) atomicMax(slot, __float_as_uint(m));
}

// ---------- maxabs over gathered embedding rows ----------
__global__ void kGatherMax(const int* x, const int* y, const float* emb_tok, const float* emb_lab, u32* ctrl) {
  __shared__ float red[256];
  int tid = threadIdx.x;
  float mt = 0.f, ml = 0.f;
  for (int p = blockIdx.x; p < B_ * T_; p += gridDim.x)
    mt = fmaxf(mt, fabsf(emb_tok[(size_t)x[p] * 256 + tid]));
  for (int p = blockIdx.x; p < B_; p += gridDim.x)
    if (tid < 64) ml = fmaxf(ml, fabsf(emb_lab[y[p] * 64 + tid]));
  float m = bredmax(mt, red);
  if (tid == 0) atomicMax(&ctrl[7], __float_as_uint(m));
  m = bredmax(ml, red);
  if (tid == 0) atomicMax(&ctrl[8], __float_as_uint(m));
}

// ---------- per-tensor scales ----------
__global__ void kScalars(u32* ctrl) {
  float* s = (float*)(ctrl + 16);
  float mt = __uint_as_float(ctrl[2]), ml = __uint_as_float(ctrl[3]);
  float mwi = __uint_as_float(ctrl[4]), mwh = __uint_as_float(ctrl[5]), mwd = __uint_as_float(ctrl[6]);
  float mtg = __uint_as_float(ctrl[7]), mlg = __uint_as_float(ctrl[8]);
  float s_tok = fmaxf(mt, 1e-8f) / 127.f, s_lab = fmaxf(ml, 1e-8f) / 127.f;
  s[0] = s_tok; s[1] = s_lab;
  s[2] = fmaxf(mwi, 1e-8f) / 127.f;
  s[3] = fmaxf(mwh, 1e-8f) / 127.f;
  s[4] = fmaxf(mwd, 1e-8f) / 127.f;
  float qt = fminf(rintf(mtg / s_tok), 127.f) * s_tok;   // monotonicity of fq
  float ql = fminf(rintf(mlg / s_lab), 127.f) * s_lab;
  s[5] = fmaxf(fmaxf(qt, ql), 1e-8f) / 127.f;
}

// ---------- double-quantized input -> int-valued bf16, layout [t][b][d] ----------
__global__ void kBuildInp(const int* x, const int* y, const float* emb_tok, const float* emb_lab,
                          const u32* ctrl, u16* inp) {
  const float* s = (const float*)(ctrl + 16);
  float s_tok = s[0], s_lab = s[1], s_inp = s[5];
  int p = blockIdx.x, b = p >> 9, t = p & 511, d = threadIdx.x;
  float v, s1;
  if (d < 256) { v = emb_tok[(size_t)x[p] * 256 + d]; s1 = s_tok; }
  else         { v = emb_lab[y[b] * 64 + (d - 256)];  s1 = s_lab; }
  float q1 = fminf(fmaxf(rintf(v / s1), -128.f), 127.f) * s1;
  float k2 = fminf(fmaxf(rintf(q1 / s_inp), -128.f), 127.f);
  inp[((size_t)t * B_ + b) * DIN_ + d] = f2b_exact(k2);
}

// ---------- quantize Wi/Wh row-major as int-bf16; build bias ----------
__global__ void kQuantW(const float* Wi, const float* Wh, const float* bi, const float* bh,
                        const u32* ctrl, u16* wi8, u16* wh8, float* biasF) {
  const float* s = (const float*)(ctrl + 16);
  float sWi = s[2], sWh = s[3];
  const int NA = G4_ * DIN_, NB = G4_ * H_;
  int i0 = blockIdx.x * blockDim.x + threadIdx.x, st = gridDim.x * blockDim.x;
  for (int i = i0; i < NA + NB + G4_; i += st) {
    if (i < NA) {
      wi8[i] = f2b_exact(fminf(fmaxf(rintf(Wi[i] / sWi), -128.f), 127.f));
    } else if (i < NA + NB) {
      int j = i - NA;
      wh8[j] = f2b_exact(fminf(fmaxf(rintf(Wh[j] / sWh), -128.f), 127.f));
    } else {
      int r = i - NA - NB;
      biasF[r] = bi[r] + bh[r];
    }
  }
}

// ---------- persistent MFMA scan: 64 blocks x 256 threads, 8 hidden cols/block ----------
// R3 structure (4 hops, u16 hBuf via agent-scope atomics, producer-side quant, no fences)
// with ONE change: only wave 0 polls each flag hop (64 readers/line instead of 256),
// result broadcast via LDS + __syncthreads. Isolates poll-contention as the variable.
__global__ __launch_bounds__(256, 1) void kScan(
    const u16* inp8, const u16* wi8, const u16* wh8, const float* biasF,
    const u32* ctrl, u64* flag1, u64* flag2, u64* flag3, u64* flag4,
    u16* hBuf, float* resF) {
  __shared__ u16 ldsWi[20 * 64 * 8];   // B-frags [nt*10+ks][lane][8]
  __shared__ u16 ldsWh[32 * 64 * 8];   // B-frags [nt*16+ks][lane][8]
  __shared__ float actT[32][66];       // [gate-local n][batch]
  __shared__ float biasT[32];
  __shared__ float sRed[4][8];
  __shared__ float bcast[8];           // [0..5] gate maxes, [6] maxc, [7] maxhp

  const int tid = threadIdx.x, lane = tid & 63, wid = tid >> 6;
  const int quad = lane >> 4, l15 = lane & 15;
  const int blk = blockIdx.x, hb = blk * 8;
  const float* scal = (const float*)(ctrl + 16);
  const float sWi = scal[2], sWh = scal[3], s_inp = scal[5];
  const float sA = s_inp * sWi;

  // stage weight fragments into LDS (row n -> global gate row r)
  for (int fid = wid; fid < 20; fid += 4) {
    int nt = fid / 10, ks = fid - nt * 10;
    int n = nt * 16 + l15, r = (n >> 3) * 512 + hb + (n & 7);
    *(uint4*)&ldsWi[(fid * 64 + lane) * 8] = *(const uint4*)(wi8 + (size_t)r * DIN_ + ks * 32 + quad * 8);
  }
  for (int fid = wid; fid < 32; fid += 4) {
    int nt = fid >> 4, ks = fid & 15;
    int n = nt * 16 + l15, r = (n >> 3) * 512 + hb + (n & 7);
    *(uint4*)&ldsWh[(fid * 64 + lane) * 8] = *(const uint4*)(wh8 + (size_t)r * H_ + ks * 32 + quad * 8);
  }
  if (tid < 32) { int r = (tid >> 3) * 512 + hb + (tid & 7); biasT[tid] = biasF[r]; }
  __syncthreads();

  const int m0 = wid * 16;
  const int jj0 = tid & 7, b0 = tid >> 3;          // e=0 cell ownership
  const int jj1 = (tid + 256) & 7, b1 = (tid + 256) >> 3;
  float cReg[2] = {0.f, 0.f};
  float hFirst[2] = {0.f, 0.f};
  float s_h_prev = 1.0f;

  // precompute input-contribution accumulators for t=0
  f32x4 nA0 = {0.f, 0.f, 0.f, 0.f}, nA1 = {0.f, 0.f, 0.f, 0.f};
  {
    const u16* ip = inp8 + ((size_t)(m0 + l15)) * DIN_ + quad * 8;
#pragma unroll
    for (int ks = 0; ks < 10; ++ks) {
      short8 a = *(const short8*)(ip + ks * 32);
      nA0 = MFMA(a, *(const short8*)&ldsWi[(ks * 64 + lane) * 8], nA0);
      nA1 = MFMA(a, *(const short8*)&ldsWi[((10 + ks) * 64 + lane) * 8], nA1);
    }
  }

  for (int t = 0; t < T_; ++t) {
    const u32 sq = (u32)(t * 4);
    f32x4 aA0 = nA0, aA1 = nA1;

    // ===== R4 of previous step: wait for h publish (wave 0 polls) =====
    if (t > 0) {
      if (wid == 0) {
        u64* f4 = flag4 + lane * 8;
        for (;;) {
          u64 v = ld_flag(f4);
          if ((u32)(v >> 32) == sq) break;
          __builtin_amdgcn_s_sleep(2);
        }
      }
      __syncthreads();
      __builtin_amdgcn_sched_barrier(0);   // no loads hoisted above the release
    }

    // ===== stage 1: recurrent GEMM (exact integer bf16 MFMA, LLC-direct h loads) =====
    f32x4 aB0 = {0.f,0.f,0.f,0.f}, aB1 = {0.f,0.f,0.f,0.f};
    const u16* hp = hBuf + (size_t)(m0 + l15) * H_ + quad * 8;
#pragma unroll
    for (int ks = 0; ks < 16; ++ks) {
      u64 w0 = ld_h64(hp + ks * 32);
      u64 w1 = ld_h64(hp + ks * 32 + 4);
      short8 a;
      ((u64*)&a)[0] = w0;
      ((u64*)&a)[1] = w1;
      aB0 = MFMA(a, *(const short8*)&ldsWh[(ks * 64 + lane) * 8], aB0);
      aB1 = MFMA(a, *(const short8*)&ldsWh[((16 + ks) * 64 + lane) * 8], aB1);
    }
    const float sB_ = s_h_prev * sWh;
    float vabs = 0.f, v0mx = -3e38f, v1mx = -3e38f, v1mn = 3e38f;
#pragma unroll
    for (int reg = 0; reg < 4; ++reg) {
      int m = m0 + quad * 4 + reg;
      float p0 = biasT[l15] + sA * aA0[reg] + sB_ * aB0[reg];        // n = l15   (gates i|f)
      float p1 = biasT[16 + l15] + sA * aA1[reg] + sB_ * aB1[reg];   // n = 16+l15 (gates g|o)
      actT[l15][m] = p0; actT[16 + l15][m] = p1;
      vabs = fmaxf(vabs, fmaxf(fabsf(p0), fabsf(p1)));
      v0mx = fmaxf(v0mx, p0);
      v1mx = fmaxf(v1mx, p1);
      v1mn = fminf(v1mn, p1);
    }
    // 6 partials: preabs, max_i, max_f, max_o, max_g, max(-g)
    bool lo = (l15 < 8);
    float q[6];
    q[0] = vabs;
    q[1] = lo ? v0mx : -3e38f;
    q[2] = lo ? -3e38f : v0mx;
    q[3] = lo ? -3e38f : v1mx;
    q[4] = lo ? v1mx : -3e38f;
    q[5] = lo ? -v1mn : -3e38f;
#pragma unroll
    for (int d = 1; d < 64; d <<= 1) {
#pragma unroll
      for (int k = 0; k < 6; ++k) q[k] = fmaxf(q[k], __shfl_xor(q[k], d, 64));
    }
    if (lane == 0) {
#pragma unroll
      for (int k = 0; k < 6; ++k) sRed[wid][k] = q[k];
    }
    __syncthreads();   // S1: sRed + actT ready
    if (tid < 6) {
      float m = fmaxf(fmaxf(sRed[0][tid], sRed[1][tid]), fmaxf(sRed[2][tid], sRed[3][tid]));
      st_flag(flag1 + blk * 8 + tid, (((u64)(sq + 1)) << 32) | (u64)__float_as_uint(m));
    }
    // poll R1: wave 0 only; lane l watches block l; butterfly; broadcast via LDS
    if (wid == 0) {
      u64 a0, a1, a2, a3, a4, a5;
      u64* fb = flag1 + lane * 8;
      const u32 e = sq + 1;
      for (;;) {
        a0 = ld_flag(fb + 0); a1 = ld_flag(fb + 1); a2 = ld_flag(fb + 2);
        a3 = ld_flag(fb + 3); a4 = ld_flag(fb + 4); a5 = ld_flag(fb + 5);
        if ((u32)(a0 >> 32) == e && (u32)(a1 >> 32) == e && (u32)(a2 >> 32) == e &&
            (u32)(a3 >> 32) == e && (u32)(a4 >> 32) == e && (u32)(a5 >> 32) == e) break;
        __builtin_amdgcn_s_sleep(2);
      }
      float g0 = __uint_as_float((u32)a0), g1 = __uint_as_float((u32)a1),
            g2 = __uint_as_float((u32)a2), g3 = __uint_as_float((u32)a3),
            g4 = __uint_as_float((u32)a4), g5 = __uint_as_float((u32)a5);
#pragma unroll
      for (int d = 1; d < 64; d <<= 1) {
        g0 = fmaxf(g0, __shfl_xor(g0, d, 64));
        g1 = fmaxf(g1, __shfl_xor(g1, d, 64));
        g2 = fmaxf(g2, __shfl_xor(g2, d, 64));
        g3 = fmaxf(g3, __shfl_xor(g3, d, 64));
        g4 = fmaxf(g4, __shfl_xor(g4, d, 64));
        g5 = fmaxf(g5, __shfl_xor(g5, d, 64));
      }
      if (lane == 0) {
        bcast[0] = g0; bcast[1] = g1; bcast[2] = g2;
        bcast[3] = g3; bcast[4] = g4; bcast[5] = g5;
      }
    }
    __syncthreads();   // S2: bcast ready
    const float s_g = fmaxf(bcast[0], 1e-8f) / 127.f;
    const float mi = bcast[1], mf = bcast[2], mo = bcast[3];
    const float mg = bcast[4], mgn = -bcast[5];   // mgn = min of g-gate pre
    const float s_i = fmaxf(sigm(fqv(mi, s_g)), 1e-8f) / 255.f;
    const float s_f = fmaxf(sigm(fqv(mf, s_g)), 1e-8f) / 255.f;
    const float s_o = fmaxf(sigm(fqv(mo, s_g)), 1e-8f) / 255.f;
    const float ga = fmaxf(fabsf(fqv(mg, s_g)), fabsf(fqv(mgn, s_g)));
    const float s_gt = fmaxf(tanhf(ga), 1e-8f) / 127.f;

    // ===== stage 2: activations + cell update (c in registers) =====
    float oqv[2];
    {
      float vi = sigm(fqv(actT[jj0][b0], s_g));
      float vf = sigm(fqv(actT[8 + jj0][b0], s_g));
      float vg = tanhf(fqv(actT[16 + jj0][b0], s_g));
      float vo = sigm(fqv(actT[24 + jj0][b0], s_g));
      float iq = fminf(fmaxf(rintf(vi / s_i), 0.f), 255.f) * s_i;
      float fq = fminf(fmaxf(rintf(vf / s_f), 0.f), 255.f) * s_f;
      float gq = fminf(fmaxf(rintf(vg / s_gt), -128.f), 127.f) * s_gt;
      oqv[0] = fminf(fmaxf(rintf(vo / s_o), 0.f), 255.f) * s_o;
      cReg[0] = fq * cReg[0] + iq * gq;
      vi = sigm(fqv(actT[jj1][b1], s_g));
      vf = sigm(fqv(actT[8 + jj1][b1], s_g));
      vg = tanhf(fqv(actT[16 + jj1][b1], s_g));
      vo = sigm(fqv(actT[24 + jj1][b1], s_g));
      iq = fminf(fmaxf(rintf(vi / s_i), 0.f), 255.f) * s_i;
      fq = fminf(fmaxf(rintf(vf / s_f), 0.f), 255.f) * s_f;
      gq = fminf(fmaxf(rintf(vg / s_gt), -128.f), 127.f) * s_gt;
      oqv[1] = fminf(fmaxf(rintf(vo / s_o), 0.f), 255.f) * s_o;
      cReg[1] = fq * cReg[1] + iq * gq;
    }
    float lm = wredmax(fmaxf(fabsf(cReg[0]), fabsf(cReg[1])));
    if (lane == 0) sRed[wid][0] = lm;
    __syncthreads();   // S3
    if (tid == 0) {
      float m = fmaxf(fmaxf(sRed[0][0], sRed[1][0]), fmaxf(sRed[2][0], sRed[3][0]));
      st_flag(flag2 + blk * 8, (((u64)(sq + 2)) << 32) | (u64)__float_as_uint(m));
    }
    if (wid == 0) {
      u64* f2 = flag2 + lane * 8;
      u64 v;
      for (;;) {
        v = ld_flag(f2);
        if ((u32)(v >> 32) == sq + 2) break;
        __builtin_amdgcn_s_sleep(2);
      }
      float mc = __uint_as_float((u32)v);
#pragma unroll
      for (int d = 1; d < 64; d <<= 1) mc = fmaxf(mc, __shfl_xor(mc, d, 64));
      if (lane == 0) bcast[6] = mc;
    }
    __syncthreads();   // S4
    const float maxc = bcast[6];
    const float s_t = fmaxf(tanhf(maxc), 1e-8f) / 127.f;   // max|tanh c| = tanh(max|c|)

    // ===== stage 3: tq = fq(tanh c); hp = oq*tq =====
    float hpv[2];
    hpv[0] = oqv[0] * fqv(tanhf(cReg[0]), s_t);
    hpv[1] = oqv[1] * fqv(tanhf(cReg[1]), s_t);
    lm = wredmax(fmaxf(fabsf(hpv[0]), fabsf(hpv[1])));
    if (lane == 0) sRed[wid][0] = lm;
    __syncthreads();   // S5
    if (tid == 0) {
      float m = fmaxf(fmaxf(sRed[0][0], sRed[1][0]), fmaxf(sRed[2][0], sRed[3][0]));
      st_flag(flag3 + blk * 8, (((u64)(sq + 3)) << 32) | (u64)__float_as_uint(m));
    }
    if (wid == 0) {
      u64* f3 = flag3 + lane * 8;
      u64 v;
      for (;;) {
        v = ld_flag(f3);
        if ((u32)(v >> 32) == sq + 3) break;
        __builtin_amdgcn_s_sleep(2);
      }
      float mh = __uint_as_float((u32)v);
#pragma unroll
      for (int d = 1; d < 64; d <<= 1) mh = fmaxf(mh, __shfl_xor(mh, d, 64));
      if (lane == 0) bcast[7] = mh;
    }
    __syncthreads();   // S6
    const float s_h = fmaxf(bcast[7], 1e-8f) / 127.f;

    // ===== stage 4: h = fq(hp); publish int h via LLC-direct stores =====
    {
      float hi = fminf(fmaxf(rintf(hpv[0] / s_h), -128.f), 127.f);
      st_h(hBuf + b0 * H_ + hb + jj0, f2b_exact(hi));
      float hv = hi * s_h;
      if (t == 0) hFirst[0] = hv;
      if (t == T_ - 1) resF[b0 * H_ + hb + jj0] = 0.5f * (hFirst[0] + hv);
      hi = fminf(fmaxf(rintf(hpv[1] / s_h), -128.f), 127.f);
      st_h(hBuf + b1 * H_ + hb + jj1, f2b_exact(hi));
      hv = hi * s_h;
      if (t == 0) hFirst[1] = hv;
      if (t == T_ - 1) resF[b1 * H_ + hb + jj1] = 0.5f * (hFirst[1] + hv);
    }
    s_h_prev = s_h;
    if (t < T_ - 1) {
      __syncthreads();   // vmcnt(0) drain: all LLC-direct h stores performed
      if (tid == 0) st_flag(flag4 + blk * 8, (((u64)(sq + 4)) << 32) | 1u);
      // input-contribution GEMM for t+1: independent of h, executes under the barrier wait
      nA0 = (f32x4){0.f, 0.f, 0.f, 0.f};
      nA1 = (f32x4){0.f, 0.f, 0.f, 0.f};
      const u16* ip = inp8 + ((size_t)(t + 1) * B_ + m0 + l15) * DIN_ + quad * 8;
#pragma unroll
      for (int ks = 0; ks < 10; ++ks) {
        short8 a = *(const short8*)(ip + ks * 32);
        nA0 = MFMA(a, *(const short8*)&ldsWi[(ks * 64 + lane) * 8], nA0);
        nA1 = MFMA(a, *(const short8*)&ldsWi[((10 + ks) * 64 + lane) * 8], nA1);
      }
    }
  }
}

// ---------- decode GEMM: logits = result @ fq(Wdec)^T ----------
__global__ __launch_bounds__(256) void kDecode(const float* resF, const float* Wdec,
                                               const u32* ctrl, float* logits) {
  const float sWd = ((const float*)(ctrl + 16))[4];
  int c = blockIdx.x * 256 + threadIdx.x;
  if (c >= NTOK_) return;
  const float4* wrow = (const float4*)(Wdec + (size_t)c * H_);
  float acc[64];
#pragma unroll
  for (int rr = 0; rr < 64; rr++) acc[rr] = 0.f;
  for (int k4 = 0; k4 < H_ / 4; k4++) {
    float4 w = wrow[k4];
    float w0 = fminf(fmaxf(rintf(w.x / sWd), -128.f), 127.f) * sWd;
    float w1 = fminf(fmaxf(rintf(w.y / sWd), -128.f), 127.f) * sWd;
    float w2 = fminf(fmaxf(rintf(w.z / sWd), -128.f), 127.f) * sWd;
    float w3 = fminf(fmaxf(rintf(w.w / sWd), -128.f), 127.f) * sWd;
    const float* rp = resF + k4 * 4;
#pragma unroll
    for (int rr = 0; rr < 64; rr++) {
      acc[rr] += rp[rr * H_ + 0] * w0 + rp[rr * H_ + 1] * w1 +
                 rp[rr * H_ + 2] * w2 + rp[rr * H_ + 3] * w3;
    }
  }
#pragma unroll
  for (int rr = 0; rr < 64; rr++) logits[(size_t)rr * NTOK_ + c] = acc[rr];
}

// ---------- per-row log-softmax NLL ----------
__global__ void kLoss(const float* logits, const int* x_pred, float* nll) {
  __shared__ float red[256];
  int b = blockIdx.x, tid = threadIdx.x;
  const float* row = logits + (size_t)b * NTOK_;
  float m = -3e38f;
  for (int i = tid; i < NTOK_; i += 256) m = fmaxf(m, row[i]);
  m = bredmax(m, red);
  float s = 0.f;
  for (int i = tid; i < NTOK_; i += 256) s += expf(row[i] - m);
  red[tid] = s; __syncthreads();
  for (int st = 128; st > 0; st >>= 1) { if (tid < st) red[tid] += red[tid + st]; __syncthreads(); }
  if (tid == 0) nll[b] = m + logf(red[0]) - row[x_pred[b]];
}

__global__ void kFinal(const float* nll, float* out) {
  float s = 0.f;
  for (int i = 0; i < B_; i++) s += nll[i];
  out[0] = s / 64.f;
}

extern "C" void kernel_launch(void* const* d_in, const int* in_sizes, int n_in,
                              void* d_out, int out_size, void* d_ws, size_t ws_size,
                              hipStream_t stream) {
  const int* x      = (const int*)d_in[0];
  const int* x_pred = (const int*)d_in[1];
  const int* y_ext  = (const int*)d_in[2];
  const float* emb_tok = (const float*)d_in[3];
  const float* emb_lab = (const float*)d_in[4];
  const float* Wi   = (const float*)d_in[5];
  const float* Wh   = (const float*)d_in[6];
  const float* bi   = (const float*)d_in[7];
  const float* bh   = (const float*)d_in[8];
  const float* Wdec = (const float*)d_in[9];

  char* W = (char*)d_ws;
  u32* ctrl    = (u32*)(W + OFF_CTRL);
  u64* flag1   = (u64*)(W + OFF_FLAG1);
  u64* flag2   = (u64*)(W + OFF_FLAG2);
  u64* flag3   = (u64*)(W + OFF_FLAG3);
  u64* flag4   = (u64*)(W + OFF_FLAG4);
  float* nll   = (float*)(W + OFF_NLL);
  float* biasF = (float*)(W + OFF_BIAS);
  u16* hBuf    = (u16*)(W + OFF_HBUF);
  float* resF  = (float*)(W + OFF_RESF);
  u16* wi8     = (u16*)(W + OFF_WI8);
  u16* wh8     = (u16*)(W + OFF_WH8);
  u16* inp     = (u16*)(W + OFF_INP);
  float* logits = (float*)(W + OFF_LOG);

  kInit<<<128, 256, 0, stream>>>(ctrl, (u32*)hBuf);
  kMaxAbs<<<1024, 256, 0, stream>>>(emb_tok, NTOK_ * 256 / 4, ctrl + 2);
  kMaxAbs<<<1, 256, 0, stream>>>(emb_lab, 10 * 64 / 4, ctrl + 3);
  kMaxAbs<<<320, 256, 0, stream>>>(Wi, G4_ * DIN_ / 4, ctrl + 4);
  kMaxAbs<<<512, 256, 0, stream>>>(Wh, G4_ * H_ / 4, ctrl + 5);
  kMaxAbs<<<1024, 256, 0, stream>>>(Wdec, NTOK_ * H_ / 4, ctrl + 6);
  kGatherMax<<<256, 256, 0, stream>>>(x, y_ext, emb_tok, emb_lab, ctrl);
  kScalars<<<1, 1, 0, stream>>>(ctrl);
  kBuildInp<<<B_ * T_, DIN_, 0, stream>>>(x, y_ext, emb_tok, emb_lab, ctrl, inp);
  kQuantW<<<4096, 256, 0, stream>>>(Wi, Wh, bi, bh, ctrl, wi8, wh8, biasF);

  kScan<<<P_, 256, 0, stream>>>(inp, wi8, wh8, biasF, ctrl, flag1, flag2, flag3, flag4, hBuf, resF);

  kDecode<<<(NTOK_ + 255) / 256, 256, 0, stream>>>(resF, Wdec, ctrl, logits);
  kLoss<<<B_, 256, 0, stream>>>(logits, x_pred, nll);
  kFinal<<<1, 1, 0, stream>>>(nll, (float*)d_out);
}